// Round 1
// baseline (54.575 us; speedup 1.0000x reference)
//
#include <hip/hip_runtime.h>
#include <math.h>

// ---------------------------------------------------------------------------
// QCNN forward, analytic form.
//
// state after build_state = v(theta,phi)^{tensor 8}, v = [c e^{-i phi/2}, s e^{i phi/2}],
// c = cos(theta/2), s = sin(theta/2).  Amplitude of basis index i (qubit w = bit 7-w):
//   a_i = c^{8-k} s^k e^{i phi (k-4)},  k = popcount(i).
// The rest of the circuit is a fixed unitary U. With M_w = U^dag Z_w U:
//   feat_w = sum_{p,q} S_w[p,q] c^{16-p-q} s^{p+q} e^{i phi (q-p)}
//   S_w[p,q] = sum_k z_k conj(G[k,p]) G[k,q],  G[:,p] = U * (sum_{popc(j)=p} e_j)
// Kernel 1 computes G by simulating the circuit on the 9 indicator states and
// reduces the two 9x9 tables S_3, S_7 into d_ws. Kernel 2 evaluates per batch.
// ---------------------------------------------------------------------------

typedef float2 c32;

#define NS 9          // number of popcount classes / simulated states
#define NT 256        // threads in precompute block
#define SP 257        // padded state stride (float2 units) -> distinct banks per p

// one-qubit gate on bit-mask m applied to all NS states in LDS
__device__ __forceinline__ void g1(float2* st, int tid, int m,
                                   c32 u00, c32 u01, c32 u10, c32 u11) {
  for (int task = tid; task < NS * 128; task += NT) {
    int p = task >> 7, pr = task & 127;
    int lo = pr & (m - 1);
    int k0 = ((pr ^ lo) << 1) | lo;          // insert 0 at bit of m
    int i0 = p * SP + k0, i1 = i0 + m;
    c32 a = st[i0], b = st[i1];
    c32 n0 = make_float2(u00.x*a.x - u00.y*a.y + u01.x*b.x - u01.y*b.y,
                         u00.x*a.y + u00.y*a.x + u01.x*b.y + u01.y*b.x);
    c32 n1 = make_float2(u10.x*a.x - u10.y*a.y + u11.x*b.x - u11.y*b.y,
                         u10.x*a.y + u10.y*a.x + u11.x*b.y + u11.y*b.x);
    st[i0] = n0; st[i1] = n1;
  }
  __syncthreads();
}

// CNOT control-mask mc, target-mask mt
__device__ __forceinline__ void gcx(float2* st, int tid, int mc, int mt) {
  int m1 = mc < mt ? mc : mt;
  int m2 = mc < mt ? mt : mc;
  for (int task = tid; task < NS * 64; task += NT) {
    int p = task >> 6, pr = task & 63;
    int lo  = pr & (m1 - 1);
    int t1  = ((pr ^ lo) << 1) | lo;         // insert 0 at lower mask bit
    int lo2 = t1 & (m2 - 1);
    int k   = (((t1 ^ lo2) << 1) | lo2) | mc; // insert 0 at upper bit, set control=1
    int i0 = p * SP + k, i1 = i0 + mt;
    c32 a = st[i0];
    st[i0] = st[i1];
    st[i1] = a;
  }
  __syncthreads();
}

__device__ __forceinline__ void rz_g(float2* st, int tid, int m, float t) {
  float c = cosf(0.5f * t), s = sinf(0.5f * t);
  // Rz(t) = diag(e^{-it/2}, e^{it/2})
  g1(st, tid, m, make_float2(c, -s), make_float2(0.f, 0.f),
                 make_float2(0.f, 0.f), make_float2(c, s));
}

__device__ __forceinline__ void ry_g(float2* st, int tid, int m, float t) {
  float c = cosf(0.5f * t), s = sinf(0.5f * t);
  g1(st, tid, m, make_float2(c, 0.f), make_float2(-s, 0.f),
                 make_float2(s, 0.f), make_float2(c, 0.f));
}

__device__ __forceinline__ void u3_g(float2* st, int tid, int w,
                                     float t, float p, float l) {
  float c = cosf(0.5f * t), s = sinf(0.5f * t);
  int m = 1 << (7 - w);
  g1(st, tid, m,
     make_float2(c, 0.f),
     make_float2(-cosf(l) * s, -sinf(l) * s),
     make_float2(cosf(p) * s,  sinf(p) * s),
     make_float2(cosf(p + l) * c, sinf(p + l) * c));
}

__device__ __forceinline__ void block_g(float2* st, int tid, int a, int b,
                                        float rzp, float ry1, float ry2, int fin) {
  int ma = 1 << (7 - a), mb = 1 << (7 - b), mf = 1 << (7 - fin);
  const float Q = 0.70710678118654752f;
  // Rz(-pi/2) on a: diag(e^{+i pi/4}, e^{-i pi/4})
  g1(st, tid, ma, make_float2(Q, Q), make_float2(0.f, 0.f),
                  make_float2(0.f, 0.f), make_float2(Q, -Q));
  gcx(st, tid, ma, mb);
  rz_g(st, tid, mb, rzp);
  ry_g(st, tid, ma, ry1);
  gcx(st, tid, mb, ma);
  ry_g(st, tid, ma, ry2);
  gcx(st, tid, ma, mb);
  // Rz(pi/2) on fin: diag(e^{-i pi/4}, e^{+i pi/4})
  g1(st, tid, mf, make_float2(Q, -Q), make_float2(0.f, 0.f),
                  make_float2(0.f, 0.f), make_float2(Q, Q));
}

__global__ __launch_bounds__(NT)
void qcnn_precompute(const float* __restrict__ rz, const float* __restrict__ ry,
                     const float* __restrict__ u3, float* __restrict__ S_out) {
  __shared__ float2 st[NS * SP];
  int tid = threadIdx.x;
  for (int idx = tid; idx < NS * 256; idx += NT) {
    int p = idx >> 8, k = idx & 255;
    st[p * SP + k] = make_float2((__popc(k) == p) ? 1.f : 0.f, 0.f);
  }
  __syncthreads();

  block_g(st, tid, 1, 0, rz[1],  ry[0],  ry[1],  0);
  block_g(st, tid, 3, 2, rz[4],  ry[2],  ry[3],  2);
  block_g(st, tid, 5, 4, rz[7],  ry[4],  ry[5],  4);
  block_g(st, tid, 7, 6, rz[10], ry[6],  ry[7],  6);
  u3_g(st, tid, 1, u3[0],  u3[1],  u3[2]);
  u3_g(st, tid, 3, u3[3],  u3[4],  u3[5]);
  u3_g(st, tid, 5, u3[6],  u3[7],  u3[8]);
  u3_g(st, tid, 7, u3[9],  u3[10], u3[11]);
  block_g(st, tid, 3, 1, rz[13], ry[8],  ry[9],  1);
  block_g(st, tid, 7, 5, rz[16], ry[10], ry[11], 1);  // fin = 1
  block_g(st, tid, 5, 3, rz[19], ry[12], ry[13], 3);
  u3_g(st, tid, 3, u3[12], u3[13], u3[14]);
  u3_g(st, tid, 7, u3[15], u3[16], u3[17]);

  // st[p*SP + k] = G[k][p].  Reduce S_w[p][q] = sum_k z_k conj(G[k,p]) G[k,q].
  if (tid < 2 * 81) {
    int f   = (tid < 81) ? 0 : 1;      // 0 -> qubit 3, 1 -> qubit 7
    int idx = tid - f * 81;
    int p = idx / 9, q = idx % 9;
    int zb = f ? 1 : 16;               // qubit3 -> bit 4, qubit7 -> bit 0
    float sr = 0.f, si = 0.f;
    for (int k = 0; k < 256; ++k) {
      float z = (k & zb) ? -1.f : 1.f;
      c32 a = st[p * SP + k], b = st[q * SP + k];
      sr += z * (a.x * b.x + a.y * b.y);
      si += z * (a.x * b.y - a.y * b.x);
    }
    // float4 per pair: (S3.re, S3.im, S7.re, S7.im)
    S_out[idx * 4 + f * 2 + 0] = sr;
    S_out[idx * 4 + f * 2 + 1] = si;
  }
}

__global__ __launch_bounds__(256)
void qcnn_eval(const float* __restrict__ x, const float4* __restrict__ S,
               const float* __restrict__ W1, const float* __restrict__ b1,
               const float* __restrict__ W2, const float* __restrict__ b2,
               float* __restrict__ out, int B) {
  __shared__ float4 sh[81];
  int tid = threadIdx.x;
  if (tid < 81) sh[tid] = S[tid];
  __syncthreads();

  int i = blockIdx.x * 256 + tid;
  if (i >= B) return;

  float2 tp = reinterpret_cast<const float2*>(x)[i];
  float th = tp.x, ph = tp.y;

  float stt, ct;
  __sincosf(0.5f * th, &stt, &ct);

  float cp[17], sp[17];
  cp[0] = 1.f; sp[0] = 1.f;
#pragma unroll
  for (int k = 1; k < 17; ++k) { cp[k] = cp[k-1] * ct; sp[k] = sp[k-1] * stt; }

  float cd[9], sd[9];
  cd[0] = 1.f; sd[0] = 0.f;
  __sincosf(ph, &sd[1], &cd[1]);
#pragma unroll
  for (int d = 2; d < 9; ++d) {
    cd[d] = cd[d-1] * cd[1] - sd[d-1] * sd[1];
    sd[d] = sd[d-1] * cd[1] + cd[d-1] * sd[1];
  }

  float f3 = 0.f, f7 = 0.f;
#pragma unroll
  for (int p = 0; p < 9; ++p) {
#pragma unroll
    for (int q = 0; q < 9; ++q) {
      float w = cp[16 - p - q] * sp[p + q];
      int d = q - p;
      float cdd, sdd;
      if (d >= 0) { cdd = cd[d];  sdd = sd[d]; }
      else        { cdd = cd[-d]; sdd = -sd[-d]; }
      float4 s4 = sh[p * 9 + q];
      f3 += w * (s4.x * cdd - s4.y * sdd);
      f7 += w * (s4.z * cdd - s4.w * sdd);
    }
  }

  // MLP: h = tanh([f3 f7] @ W1 + b1); out = sigmoid(h @ W2 + b2)
  float acc = b2[0];
#pragma unroll
  for (int j = 0; j < 10; ++j) {
    float h = tanhf(f3 * W1[j] + f7 * W1[10 + j] + b1[j]);
    acc += h * W2[j];
  }
  out[i] = 1.f / (1.f + __expf(-acc));
}

extern "C" void kernel_launch(void* const* d_in, const int* in_sizes, int n_in,
                              void* d_out, int out_size, void* d_ws, size_t ws_size,
                              hipStream_t stream) {
  const float* x  = (const float*)d_in[0];
  const float* rz = (const float*)d_in[1];
  const float* ry = (const float*)d_in[2];
  const float* u3 = (const float*)d_in[3];
  const float* W1 = (const float*)d_in[4];
  const float* b1 = (const float*)d_in[5];
  const float* W2 = (const float*)d_in[6];
  const float* b2 = (const float*)d_in[7];
  float* S = (float*)d_ws;               // 81 * float4 = 1296 bytes

  qcnn_precompute<<<1, NT, 0, stream>>>(rz, ry, u3, S);

  int B = in_sizes[0] / 2;               // 65536
  int grid = (B + 255) / 256;
  qcnn_eval<<<grid, 256, 0, stream>>>(x, (const float4*)S, W1, b1, W2, b2,
                                      (float*)d_out, B);
}

// Round 2
// 28.498 us; speedup vs baseline: 1.9151x; 1.9151x over previous
//
#include <hip/hip_runtime.h>
#include <math.h>

// ---------------------------------------------------------------------------
// QCNN forward, analytic form.
//
// state after build_state = v(theta,phi)^{x8}, v = [c e^{-i phi/2}, s e^{i phi/2}].
// Amplitude of basis index i: a_i = c^{8-k} s^k e^{i phi (k-4)}, k = popcount(i).
// The rest of the circuit is a fixed unitary U:
//   feat_w = sum_{p,q} S_w[p,q] c^{16-p-q} s^{p+q} e^{i phi (q-p)}
//   S_w[p,q] = sum_k z_k conj(G[k,p]) G[k,q],  G[:,p] = U * (indicator popc = p)
//
// Precompute: 9 waves, one indicator state per wave, 4 amplitudes per lane in
// REGISTERS. Qubit->bit remap (popcount-invariant) puts the two highest-
// traffic qubits (q3, q5) on the in-register bits (masks 64/128, zero-comm
// register ops); the rest use __shfl_xor. No barriers during simulation.
//   masks: q0=1 q1=2 q2=4 q3=64 q4=8 q5=128 q6=16 q7=32
// ---------------------------------------------------------------------------

__device__ __forceinline__ float2 cmad2(float2 A, float2 a, float2 B, float2 b) {
  return make_float2(A.x*a.x - A.y*a.y + B.x*b.x - B.y*b.y,
                     A.x*a.y + A.y*a.x + B.x*b.y + B.y*b.x);
}

// generic 1q gate along mask M
template<int M>
__device__ __forceinline__ void gate1(float2 (&z)[4], int lane,
                                      float2 u00, float2 u01,
                                      float2 u10, float2 u11) {
  if constexpr (M < 64) {
#pragma unroll
    for (int j = 0; j < 4; ++j) {
      float2 pv = make_float2(__shfl_xor(z[j].x, M, 64),
                              __shfl_xor(z[j].y, M, 64));
      bool hi = (lane & M) != 0;
      float2 A = hi ? u11 : u00;   // coeff of own element
      float2 B = hi ? u10 : u01;   // coeff of partner
      z[j] = cmad2(A, z[j], B, pv);
    }
  } else {
    constexpr int jb = M >> 6;     // 1 or 2
#pragma unroll
    for (int j = 0; j < 4; ++j) {
      if ((j & jb) == 0) {
        float2 a = z[j], b = z[j + jb];
        z[j]      = cmad2(u00, a, u01, b);
        z[j + jb] = cmad2(u10, a, u11, b);
      }
    }
  }
}

template<int MC, int MT>
__device__ __forceinline__ void cnotg(float2 (&z)[4], int lane) {
  if constexpr (MT < 64) {
#pragma unroll
    for (int j = 0; j < 4; ++j) {
      bool active = (MC < 64) || (((j << 6) & MC) != 0);  // folds per j
      if (active) {
        float2 pv = make_float2(__shfl_xor(z[j].x, MT, 64),
                                __shfl_xor(z[j].y, MT, 64));
        bool sel = (MC >= 64) || ((lane & MC) != 0);
        z[j].x = sel ? pv.x : z[j].x;
        z[j].y = sel ? pv.y : z[j].y;
      }
    }
  } else {
    constexpr int jb = MT >> 6;
#pragma unroll
    for (int j = 0; j < 4; ++j) {
      if ((j & jb) == 0) {
        if (MC >= 64) {
          constexpr int cjb = (MC >= 64) ? (MC >> 6) : 1;
          if ((j & cjb) != 0) { float2 t = z[j]; z[j] = z[j + jb]; z[j + jb] = t; }
        } else {
          bool sel = (lane & MC) != 0;
          float2 a = z[j], b = z[j + jb];
          z[j]      = make_float2(sel ? b.x : a.x, sel ? b.y : a.y);
          z[j + jb] = make_float2(sel ? a.x : b.x, sel ? a.y : b.y);
        }
      }
    }
  }
}

template<int M>
__device__ __forceinline__ void rzg(float2 (&z)[4], int lane, float t) {
  float s, c; __sincosf(0.5f * t, &s, &c);
  gate1<M>(z, lane, make_float2(c, -s), make_float2(0.f, 0.f),
                    make_float2(0.f, 0.f), make_float2(c, s));
}

template<int M>
__device__ __forceinline__ void ryg(float2 (&z)[4], int lane, float t) {
  float s, c; __sincosf(0.5f * t, &s, &c);
  gate1<M>(z, lane, make_float2(c, 0.f), make_float2(-s, 0.f),
                    make_float2(s, 0.f), make_float2(c, 0.f));
}

template<int M>
__device__ __forceinline__ void u3g(float2 (&z)[4], int lane,
                                    float t, float p, float l) {
  float s, c;  __sincosf(0.5f * t, &s, &c);
  float sp, cp; __sincosf(p, &sp, &cp);
  float sl, cl; __sincosf(l, &sl, &cl);
  float spl, cpl; __sincosf(p + l, &spl, &cpl);
  gate1<M>(z, lane, make_float2(c, 0.f),      make_float2(-cl * s, -sl * s),
                    make_float2(cp * s, sp * s), make_float2(cpl * c, spl * c));
}

template<int MA, int MB, int MF>
__device__ __forceinline__ void blockg(float2 (&z)[4], int lane,
                                       float rzp, float ry1, float ry2) {
  const float Q = 0.70710678118654752f;
  // Rz(-pi/2) on a: diag(e^{+i pi/4}, e^{-i pi/4})
  gate1<MA>(z, lane, make_float2(Q, Q), make_float2(0.f, 0.f),
                     make_float2(0.f, 0.f), make_float2(Q, -Q));
  cnotg<MA, MB>(z, lane);
  rzg<MB>(z, lane, rzp);
  ryg<MA>(z, lane, ry1);
  cnotg<MB, MA>(z, lane);
  ryg<MA>(z, lane, ry2);
  cnotg<MA, MB>(z, lane);
  // Rz(pi/2) on fin: diag(e^{-i pi/4}, e^{+i pi/4})
  gate1<MF>(z, lane, make_float2(Q, -Q), make_float2(0.f, 0.f),
                     make_float2(0.f, 0.f), make_float2(Q, Q));
}

__global__ __launch_bounds__(576)
void qcnn_precompute(const float* __restrict__ rz, const float* __restrict__ ry,
                     const float* __restrict__ u3, float* __restrict__ S_out) {
  __shared__ float2 st[9 * 258];
  int tid = threadIdx.x;
  int p = tid >> 6, lane = tid & 63;

  float2 z[4];
#pragma unroll
  for (int j = 0; j < 4; ++j) {
    int k = (j << 6) | lane;
    z[j] = make_float2(__popc(k) == p ? 1.f : 0.f, 0.f);
  }

  // masks: q0=1 q1=2 q2=4 q3=64 q4=8 q5=128 q6=16 q7=32
  blockg<2, 1, 1>(z, lane, rz[1],  ry[0],  ry[1]);    // block(1,0) fin=0
  blockg<64, 4, 4>(z, lane, rz[4],  ry[2],  ry[3]);   // block(3,2)
  blockg<128, 8, 8>(z, lane, rz[7],  ry[4],  ry[5]);  // block(5,4)
  blockg<32, 16, 16>(z, lane, rz[10], ry[6],  ry[7]); // block(7,6)
  u3g<2>(z, lane, u3[0],  u3[1],  u3[2]);             // u3 q1
  u3g<64>(z, lane, u3[3],  u3[4],  u3[5]);            // u3 q3
  u3g<128>(z, lane, u3[6],  u3[7],  u3[8]);           // u3 q5
  u3g<32>(z, lane, u3[9],  u3[10], u3[11]);           // u3 q7
  blockg<64, 2, 2>(z, lane, rz[13], ry[8],  ry[9]);   // block(3,1) fin=1
  blockg<32, 128, 2>(z, lane, rz[16], ry[10], ry[11]);// block(7,5) fin=1
  blockg<128, 64, 64>(z, lane, rz[19], ry[12], ry[13]);// block(5,3) fin=3
  u3g<64>(z, lane, u3[12], u3[13], u3[14]);           // u3 q3
  u3g<32>(z, lane, u3[15], u3[16], u3[17]);           // u3 q7

  // dump G[:,p] to LDS, then reduce the two 9x9 Hermitian tables
#pragma unroll
  for (int j = 0; j < 4; ++j) {
    int k = (j << 6) | lane;
    st[p * 258 + k] = z[j];
  }
  __syncthreads();

  if (tid < 162) {
    int f   = tid >= 81;                 // 0 -> qubit3, 1 -> qubit7
    int idx = tid - f * 81;
    int pp = idx / 9, qq = idx % 9;
    int zb = f ? 32 : 64;                // remapped masks: q3=64, q7=32
    float sr = 0.f, si = 0.f;
    for (int k = 0; k < 256; ++k) {
      float zz = (k & zb) ? -1.f : 1.f;
      float2 a = st[pp * 258 + k], b = st[qq * 258 + k];
      sr += zz * (a.x * b.x + a.y * b.y);
      si += zz * (a.x * b.y - a.y * b.x);
    }
    S_out[idx * 4 + f * 2 + 0] = sr;
    S_out[idx * 4 + f * 2 + 1] = si;
  }
}

__global__ __launch_bounds__(256)
void qcnn_eval(const float* __restrict__ x, const float4* __restrict__ S,
               const float* __restrict__ W1, const float* __restrict__ b1,
               const float* __restrict__ W2, const float* __restrict__ b2,
               float* __restrict__ out, int B) {
  __shared__ float4 sh[81];
  int tid = threadIdx.x;
  if (tid < 81) sh[tid] = S[tid];
  __syncthreads();

  int i = blockIdx.x * 256 + tid;
  if (i >= B) return;

  float2 tp = reinterpret_cast<const float2*>(x)[i];
  float th = tp.x, ph = tp.y;

  float stt, ct;
  __sincosf(0.5f * th, &stt, &ct);

  float cp[17], sp[17];
  cp[0] = 1.f; sp[0] = 1.f;
#pragma unroll
  for (int k = 1; k < 17; ++k) { cp[k] = cp[k-1] * ct; sp[k] = sp[k-1] * stt; }

  float cd[9], sd[9];
  cd[0] = 1.f; sd[0] = 0.f;
  __sincosf(ph, &sd[1], &cd[1]);
#pragma unroll
  for (int d = 2; d < 9; ++d) {
    cd[d] = cd[d-1] * cd[1] - sd[d-1] * sd[1];
    sd[d] = sd[d-1] * cd[1] + cd[d-1] * sd[1];
  }

  float f3 = 0.f, f7 = 0.f;
#pragma unroll
  for (int p = 0; p < 9; ++p) {
#pragma unroll
    for (int q = 0; q < 9; ++q) {
      float w = cp[16 - p - q] * sp[p + q];
      int d = q - p;
      float cdd, sdd;
      if (d >= 0) { cdd = cd[d];  sdd = sd[d]; }
      else        { cdd = cd[-d]; sdd = -sd[-d]; }
      float4 s4 = sh[p * 9 + q];
      f3 += w * (s4.x * cdd - s4.y * sdd);
      f7 += w * (s4.z * cdd - s4.w * sdd);
    }
  }

  float acc = b2[0];
#pragma unroll
  for (int j = 0; j < 10; ++j) {
    float h = tanhf(f3 * W1[j] + f7 * W1[10 + j] + b1[j]);
    acc += h * W2[j];
  }
  out[i] = 1.f / (1.f + __expf(-acc));
}

extern "C" void kernel_launch(void* const* d_in, const int* in_sizes, int n_in,
                              void* d_out, int out_size, void* d_ws, size_t ws_size,
                              hipStream_t stream) {
  const float* x  = (const float*)d_in[0];
  const float* rz = (const float*)d_in[1];
  const float* ry = (const float*)d_in[2];
  const float* u3 = (const float*)d_in[3];
  const float* W1 = (const float*)d_in[4];
  const float* b1 = (const float*)d_in[5];
  const float* W2 = (const float*)d_in[6];
  const float* b2 = (const float*)d_in[7];
  float* S = (float*)d_ws;               // 81 * float4 = 1296 bytes

  qcnn_precompute<<<1, 576, 0, stream>>>(rz, ry, u3, S);

  int B = in_sizes[0] / 2;               // 65536
  int grid = (B + 255) / 256;
  qcnn_eval<<<grid, 256, 0, stream>>>(x, (const float4*)S, W1, b1, W2, b2,
                                      (float*)d_out, B);
}

// Round 3
// 25.684 us; speedup vs baseline: 2.1249x; 1.1096x over previous
//
#include <hip/hip_runtime.h>
#include <math.h>

// ---------------------------------------------------------------------------
// QCNN forward, analytic form — single fused kernel.
//
// state after build_state = v(theta,phi)^{x8}, v = [c e^{-i phi/2}, s e^{i phi/2}].
// Amplitude of basis index i: a_i = c^{8-k} s^k e^{i phi (k-4)}, k = popcount(i).
// Rest of circuit = fixed unitary U:
//   feat_w = sum_{p,q} S_w[p,q] c^{16-p-q} s^{p+q} e^{i phi (q-p)}
//   S_w[p,q] = sum_k z_k conj(G[k,p]) G[k,q],  G[:,p] = U*(indicator popc = p)
// S is Hermitian -> only p<=q needed (off-diag terms doubled):
//   feat = sum_{p<=q} w_pq * mul * (Re S cos(d phi) - Im S sin(d phi)), d=q-p.
//
// Each block redundantly computes S (cheap: ~2us of register/shfl work), so
// there is exactly ONE kernel launch and no inter-kernel dependency.
// Qubit->bit remap (popcount-invariant): q0=1 q1=2 q2=4 q3=64 q4=8 q5=128
// q6=16 q7=32  (high-traffic q3,q5 on in-register bits; zero-comm gates).
// ---------------------------------------------------------------------------

__device__ __forceinline__ float2 cmad2(float2 A, float2 a, float2 B, float2 b) {
  return make_float2(A.x*a.x - A.y*a.y + B.x*b.x - B.y*b.y,
                     A.x*a.y + A.y*a.x + B.x*b.y + B.y*b.x);
}

template<int M>
__device__ __forceinline__ void gate1(float2 (&z)[4], int lane,
                                      float2 u00, float2 u01,
                                      float2 u10, float2 u11) {
  if constexpr (M < 64) {
#pragma unroll
    for (int j = 0; j < 4; ++j) {
      float2 pv = make_float2(__shfl_xor(z[j].x, M, 64),
                              __shfl_xor(z[j].y, M, 64));
      bool hi = (lane & M) != 0;
      float2 A = hi ? u11 : u00;
      float2 B = hi ? u10 : u01;
      z[j] = cmad2(A, z[j], B, pv);
    }
  } else {
    constexpr int jb = M >> 6;
#pragma unroll
    for (int j = 0; j < 4; ++j) {
      if ((j & jb) == 0) {
        float2 a = z[j], b = z[j + jb];
        z[j]      = cmad2(u00, a, u01, b);
        z[j + jb] = cmad2(u10, a, u11, b);
      }
    }
  }
}

template<int MC, int MT>
__device__ __forceinline__ void cnotg(float2 (&z)[4], int lane) {
  if constexpr (MT < 64) {
#pragma unroll
    for (int j = 0; j < 4; ++j) {
      bool active = (MC < 64) || (((j << 6) & MC) != 0);
      if (active) {
        float2 pv = make_float2(__shfl_xor(z[j].x, MT, 64),
                                __shfl_xor(z[j].y, MT, 64));
        bool sel = (MC >= 64) || ((lane & MC) != 0);
        z[j].x = sel ? pv.x : z[j].x;
        z[j].y = sel ? pv.y : z[j].y;
      }
    }
  } else {
    constexpr int jb = MT >> 6;
#pragma unroll
    for (int j = 0; j < 4; ++j) {
      if ((j & jb) == 0) {
        if (MC >= 64) {
          constexpr int cjb = MC >> 6;
          if ((j & cjb) != 0) { float2 t = z[j]; z[j] = z[j + jb]; z[j + jb] = t; }
        } else {
          bool sel = (lane & MC) != 0;
          float2 a = z[j], b = z[j + jb];
          z[j]      = make_float2(sel ? b.x : a.x, sel ? b.y : a.y);
          z[j + jb] = make_float2(sel ? a.x : b.x, sel ? a.y : b.y);
        }
      }
    }
  }
}

template<int M>
__device__ __forceinline__ void rzg(float2 (&z)[4], int lane, float t) {
  float s, c; __sincosf(0.5f * t, &s, &c);
  gate1<M>(z, lane, make_float2(c, -s), make_float2(0.f, 0.f),
                    make_float2(0.f, 0.f), make_float2(c, s));
}

template<int M>
__device__ __forceinline__ void ryg(float2 (&z)[4], int lane, float t) {
  float s, c; __sincosf(0.5f * t, &s, &c);
  gate1<M>(z, lane, make_float2(c, 0.f), make_float2(-s, 0.f),
                    make_float2(s, 0.f), make_float2(c, 0.f));
}

template<int M>
__device__ __forceinline__ void u3g(float2 (&z)[4], int lane,
                                    float t, float p, float l) {
  float s, c;  __sincosf(0.5f * t, &s, &c);
  float sp, cp; __sincosf(p, &sp, &cp);
  float sl, cl; __sincosf(l, &sl, &cl);
  float spl, cpl; __sincosf(p + l, &spl, &cpl);
  gate1<M>(z, lane, make_float2(c, 0.f),        make_float2(-cl * s, -sl * s),
                    make_float2(cp * s, sp * s), make_float2(cpl * c, spl * c));
}

template<int MA, int MB, int MF>
__device__ __forceinline__ void blockg(float2 (&z)[4], int lane,
                                       float rzp, float ry1, float ry2) {
  const float Q = 0.70710678118654752f;
  gate1<MA>(z, lane, make_float2(Q, Q), make_float2(0.f, 0.f),
                     make_float2(0.f, 0.f), make_float2(Q, -Q));
  cnotg<MA, MB>(z, lane);
  rzg<MB>(z, lane, rzp);
  ryg<MA>(z, lane, ry1);
  cnotg<MB, MA>(z, lane);
  ryg<MA>(z, lane, ry2);
  cnotg<MA, MB>(z, lane);
  gate1<MF>(z, lane, make_float2(Q, -Q), make_float2(0.f, 0.f),
                     make_float2(0.f, 0.f), make_float2(Q, Q));
}

__device__ __forceinline__ float fast_tanh(float x) {
  float e = __expf(2.f * x);
  return 1.f - 2.f / (e + 1.f);
}

#define SSTR 258   // float2 stride per state row

__global__ __launch_bounds__(576)
void qcnn_fused(const float* __restrict__ x, const float* __restrict__ rz,
                const float* __restrict__ ry, const float* __restrict__ u3,
                const float* __restrict__ W1, const float* __restrict__ b1,
                const float* __restrict__ W2, const float* __restrict__ b2,
                float* __restrict__ out, int B) {
  __shared__ float2 st[9 * SSTR];
  __shared__ float4 Stab[45];
  int tid = threadIdx.x;
  int p = tid >> 6, lane = tid & 63;

  // ---- simulate indicator state p (one state per wave, amplitudes in regs)
  float2 z[4];
#pragma unroll
  for (int j = 0; j < 4; ++j) {
    int k = (j << 6) | lane;
    z[j] = make_float2(__popc(k) == p ? 1.f : 0.f, 0.f);
  }

  blockg<2, 1, 1>(z, lane, rz[1],  ry[0],  ry[1]);     // block(1,0) fin=0
  blockg<64, 4, 4>(z, lane, rz[4],  ry[2],  ry[3]);    // block(3,2)
  blockg<128, 8, 8>(z, lane, rz[7],  ry[4],  ry[5]);   // block(5,4)
  blockg<32, 16, 16>(z, lane, rz[10], ry[6],  ry[7]);  // block(7,6)
  u3g<2>(z, lane, u3[0],  u3[1],  u3[2]);              // u3 q1
  u3g<64>(z, lane, u3[3],  u3[4],  u3[5]);             // u3 q3
  u3g<128>(z, lane, u3[6],  u3[7],  u3[8]);            // u3 q5
  u3g<32>(z, lane, u3[9],  u3[10], u3[11]);            // u3 q7
  blockg<64, 2, 2>(z, lane, rz[13], ry[8],  ry[9]);    // block(3,1) fin=1
  blockg<32, 128, 2>(z, lane, rz[16], ry[10], ry[11]); // block(7,5) fin=1
  blockg<128, 64, 64>(z, lane, rz[19], ry[12], ry[13]);// block(5,3) fin=3
  u3g<64>(z, lane, u3[12], u3[13], u3[14]);            // u3 q3
  u3g<32>(z, lane, u3[15], u3[16], u3[17]);            // u3 q7

#pragma unroll
  for (int j = 0; j < 4; ++j)
    st[p * SSTR + ((j << 6) | lane)] = z[j];
  __syncthreads();

  // ---- reduce: 45 threads, one (p<=q) pair each, both features at once.
  // k-bit5 (q7 sign) and k-bit6 (q3 sign) are constant per 32-k chunk ->
  // accumulate 4 sign-free group sums, combine at the end.
  if (tid < 45) {
    int s = tid, pp = 0, base = 0;
    while (s >= base + 9 - pp) { base += 9 - pp; ++pp; }
    int qq = pp + (s - base);

    const float2* rowp = &st[pp * SSTR];
    const float2* rowq = &st[qq * SSTR];
    float2 g[4];
#pragma unroll
    for (int t = 0; t < 4; ++t) g[t] = make_float2(0.f, 0.f);

#pragma unroll
    for (int hi = 0; hi < 8; ++hi) {
#pragma unroll
      for (int lo = 0; lo < 32; ++lo) {
        int k = hi * 32 + lo;
        float2 a = rowp[k], b = rowq[k];
        float pr = a.x * b.x + a.y * b.y;   // conj(a)*b
        float pi = a.x * b.y - a.y * b.x;
        g[hi & 3].x += pr;
        g[hi & 3].y += pi;
      }
    }
    // f3 sign = k bit6 -> groups 2,3 negative; f7 sign = k bit5 -> 1,3 negative
    float s3r = g[0].x + g[1].x - g[2].x - g[3].x;
    float s3i = g[0].y + g[1].y - g[2].y - g[3].y;
    float s7r = g[0].x - g[1].x + g[2].x - g[3].x;
    float s7i = g[0].y - g[1].y + g[2].y - g[3].y;
    float sc = (pp == qq) ? 1.f : 2.f;      // Hermitian fold
    Stab[tid] = make_float4(sc * s3r, sc * s3i, sc * s7r, sc * s7i);
  }
  __syncthreads();

  // ---- eval: 512 elements per block
  if (tid < 512) {
    int i = blockIdx.x * 512 + tid;
    if (i < B) {
      float2 tp = reinterpret_cast<const float2*>(x)[i];
      float th = tp.x, ph = tp.y;

      float stt, ct;
      __sincosf(0.5f * th, &stt, &ct);

      float cpw[17], spw[17];
      cpw[0] = 1.f; spw[0] = 1.f;
#pragma unroll
      for (int k = 1; k < 17; ++k) { cpw[k] = cpw[k-1] * ct; spw[k] = spw[k-1] * stt; }

      float cd[9], sd[9];
      cd[0] = 1.f; sd[0] = 0.f;
      __sincosf(ph, &sd[1], &cd[1]);
#pragma unroll
      for (int d = 2; d < 9; ++d) {
        cd[d] = cd[d-1] * cd[1] - sd[d-1] * sd[1];
        sd[d] = sd[d-1] * cd[1] + cd[d-1] * sd[1];
      }

      float f3 = 0.f, f7 = 0.f;
      int sidx = 0;
#pragma unroll
      for (int pp = 0; pp < 9; ++pp) {
#pragma unroll
        for (int qq = pp; qq < 9; ++qq) {
          float4 s4 = Stab[sidx]; ++sidx;
          float w = cpw[16 - pp - qq] * spw[pp + qq];
          int d = qq - pp;
          f3 += w * (s4.x * cd[d] - s4.y * sd[d]);
          f7 += w * (s4.z * cd[d] - s4.w * sd[d]);
        }
      }

      float acc = b2[0];
#pragma unroll
      for (int j = 0; j < 10; ++j) {
        float h = fast_tanh(f3 * W1[j] + f7 * W1[10 + j] + b1[j]);
        acc += h * W2[j];
      }
      out[i] = 1.f / (1.f + __expf(-acc));
    }
  }
}

extern "C" void kernel_launch(void* const* d_in, const int* in_sizes, int n_in,
                              void* d_out, int out_size, void* d_ws, size_t ws_size,
                              hipStream_t stream) {
  const float* x  = (const float*)d_in[0];
  const float* rz = (const float*)d_in[1];
  const float* ry = (const float*)d_in[2];
  const float* u3 = (const float*)d_in[3];
  const float* W1 = (const float*)d_in[4];
  const float* b1 = (const float*)d_in[5];
  const float* W2 = (const float*)d_in[6];
  const float* b2 = (const float*)d_in[7];

  int B = in_sizes[0] / 2;                 // 65536
  int grid = (B + 511) / 512;              // 128 blocks x 512 elements
  qcnn_fused<<<grid, 576, 0, stream>>>(x, rz, ry, u3, W1, b1, W2, b2,
                                       (float*)d_out, B);
}

// Round 4
// 20.614 us; speedup vs baseline: 2.6474x; 1.2459x over previous
//
#include <hip/hip_runtime.h>
#include <math.h>

// ---------------------------------------------------------------------------
// QCNN forward, analytic form — 3 dispatches.
//
// state after build_state = v(theta,phi)^{x8}, v = [c e^{-i phi/2}, s e^{i phi/2}].
// a_i = c^{8-k} s^k e^{i phi (k-4)}, k = popcount(i).  Rest of circuit = fixed U:
//   feat_w = sum_{p<=q} S_w[p,q] c^{16-p-q} s^{p+q} (Re S cos(d phi) - Im S sin(d phi))
//   S_w[p,q] = sum_k z_k conj(G[k,p]) G[k,q],  G[:,p] = U*(indicator popc = p)
//
// K1 (9 blocks x 64): one indicator state per wave, amplitudes in registers,
//     cross-lane gates via __shfl_xor; writes G[p][k] to d_ws.
// K2 (1 block x 576): wave w reduces pairs [5w..5w+4]; lanes split k (4 each),
//     float4 loads from L2, 6-level shfl tree. Writes Stab[45] float4.
// K3 (256 x 256): per-element polynomial + MLP.
//
// Qubit->bit remap (popcount-invariant): q0=1 q1=2 q2=4 q3=64 q4=8 q5=128
// q6=16 q7=32 (high-traffic q3,q5 on in-register bits).
// ---------------------------------------------------------------------------

__device__ __forceinline__ float2 cmad2(float2 A, float2 a, float2 B, float2 b) {
  return make_float2(A.x*a.x - A.y*a.y + B.x*b.x - B.y*b.y,
                     A.x*a.y + A.y*a.x + B.x*b.y + B.y*b.x);
}

template<int M>
__device__ __forceinline__ void gate1(float2 (&z)[4], int lane,
                                      float2 u00, float2 u01,
                                      float2 u10, float2 u11) {
  if constexpr (M < 64) {
#pragma unroll
    for (int j = 0; j < 4; ++j) {
      float2 pv = make_float2(__shfl_xor(z[j].x, M, 64),
                              __shfl_xor(z[j].y, M, 64));
      bool hi = (lane & M) != 0;
      float2 A = hi ? u11 : u00;
      float2 B = hi ? u10 : u01;
      z[j] = cmad2(A, z[j], B, pv);
    }
  } else {
    constexpr int jb = M >> 6;
#pragma unroll
    for (int j = 0; j < 4; ++j) {
      if ((j & jb) == 0) {
        float2 a = z[j], b = z[j + jb];
        z[j]      = cmad2(u00, a, u01, b);
        z[j + jb] = cmad2(u10, a, u11, b);
      }
    }
  }
}

template<int MC, int MT>
__device__ __forceinline__ void cnotg(float2 (&z)[4], int lane) {
  if constexpr (MT < 64) {
#pragma unroll
    for (int j = 0; j < 4; ++j) {
      bool active = (MC < 64) || (((j << 6) & MC) != 0);
      if (active) {
        float2 pv = make_float2(__shfl_xor(z[j].x, MT, 64),
                                __shfl_xor(z[j].y, MT, 64));
        bool sel = (MC >= 64) || ((lane & MC) != 0);
        z[j].x = sel ? pv.x : z[j].x;
        z[j].y = sel ? pv.y : z[j].y;
      }
    }
  } else {
    constexpr int jb = MT >> 6;
#pragma unroll
    for (int j = 0; j < 4; ++j) {
      if ((j & jb) == 0) {
        if (MC >= 64) {
          constexpr int cjb = MC >> 6;
          if ((j & cjb) != 0) { float2 t = z[j]; z[j] = z[j + jb]; z[j + jb] = t; }
        } else {
          bool sel = (lane & MC) != 0;
          float2 a = z[j], b = z[j + jb];
          z[j]      = make_float2(sel ? b.x : a.x, sel ? b.y : a.y);
          z[j + jb] = make_float2(sel ? a.x : b.x, sel ? a.y : b.y);
        }
      }
    }
  }
}

template<int M>
__device__ __forceinline__ void rzg(float2 (&z)[4], int lane, float t) {
  float s, c; __sincosf(0.5f * t, &s, &c);
  gate1<M>(z, lane, make_float2(c, -s), make_float2(0.f, 0.f),
                    make_float2(0.f, 0.f), make_float2(c, s));
}

template<int M>
__device__ __forceinline__ void ryg(float2 (&z)[4], int lane, float t) {
  float s, c; __sincosf(0.5f * t, &s, &c);
  gate1<M>(z, lane, make_float2(c, 0.f), make_float2(-s, 0.f),
                    make_float2(s, 0.f), make_float2(c, 0.f));
}

template<int M>
__device__ __forceinline__ void u3g(float2 (&z)[4], int lane,
                                    float t, float p, float l) {
  float s, c;  __sincosf(0.5f * t, &s, &c);
  float sp, cp; __sincosf(p, &sp, &cp);
  float sl, cl; __sincosf(l, &sl, &cl);
  float spl, cpl; __sincosf(p + l, &spl, &cpl);
  gate1<M>(z, lane, make_float2(c, 0.f),        make_float2(-cl * s, -sl * s),
                    make_float2(cp * s, sp * s), make_float2(cpl * c, spl * c));
}

template<int MA, int MB, int MF>
__device__ __forceinline__ void blockg(float2 (&z)[4], int lane,
                                       float rzp, float ry1, float ry2) {
  const float Q = 0.70710678118654752f;
  gate1<MA>(z, lane, make_float2(Q, Q), make_float2(0.f, 0.f),
                     make_float2(0.f, 0.f), make_float2(Q, -Q));
  cnotg<MA, MB>(z, lane);
  rzg<MB>(z, lane, rzp);
  ryg<MA>(z, lane, ry1);
  cnotg<MB, MA>(z, lane);
  ryg<MA>(z, lane, ry2);
  cnotg<MA, MB>(z, lane);
  gate1<MF>(z, lane, make_float2(Q, -Q), make_float2(0.f, 0.f),
                     make_float2(0.f, 0.f), make_float2(Q, Q));
}

__device__ __forceinline__ float fast_tanh(float x) {
  float e = __expf(2.f * x);
  return 1.f - 2.f / (e + 1.f);
}

// ---- K1: simulate one indicator state per block-wave, write G[p][k] --------
__global__ __launch_bounds__(64)
void qcnn_sim(const float* __restrict__ rz, const float* __restrict__ ry,
              const float* __restrict__ u3, float2* __restrict__ G) {
  int lane = threadIdx.x;
  int p = blockIdx.x;

  float2 z[4];
#pragma unroll
  for (int j = 0; j < 4; ++j) {
    int k = (j << 6) | lane;
    z[j] = make_float2(__popc(k) == p ? 1.f : 0.f, 0.f);
  }

  blockg<2, 1, 1>(z, lane, rz[1],  ry[0],  ry[1]);     // block(1,0) fin=0
  blockg<64, 4, 4>(z, lane, rz[4],  ry[2],  ry[3]);    // block(3,2)
  blockg<128, 8, 8>(z, lane, rz[7],  ry[4],  ry[5]);   // block(5,4)
  blockg<32, 16, 16>(z, lane, rz[10], ry[6],  ry[7]);  // block(7,6)
  u3g<2>(z, lane, u3[0],  u3[1],  u3[2]);              // u3 q1
  u3g<64>(z, lane, u3[3],  u3[4],  u3[5]);             // u3 q3
  u3g<128>(z, lane, u3[6],  u3[7],  u3[8]);            // u3 q5
  u3g<32>(z, lane, u3[9],  u3[10], u3[11]);            // u3 q7
  blockg<64, 2, 2>(z, lane, rz[13], ry[8],  ry[9]);    // block(3,1) fin=1
  blockg<32, 128, 2>(z, lane, rz[16], ry[10], ry[11]); // block(7,5) fin=1
  blockg<128, 64, 64>(z, lane, rz[19], ry[12], ry[13]);// block(5,3) fin=3
  u3g<64>(z, lane, u3[12], u3[13], u3[14]);            // u3 q3
  u3g<32>(z, lane, u3[15], u3[16], u3[17]);            // u3 q7

#pragma unroll
  for (int j = 0; j < 4; ++j)
    G[p * 256 + ((j << 6) | lane)] = z[j];
}

// ---- K2: reduce the two 9x9 Hermitian tables (45 upper-tri pairs) ----------
// wave w handles pairs 5w..5w+4; lane handles k in [4*lane, 4*lane+4).
// Z-signs in remapped bits: q3 -> k bit6 -> lane bit4; q7 -> k bit5 -> lane bit3.
__global__ __launch_bounds__(576)
void qcnn_reduce(const float2* __restrict__ G, float4* __restrict__ Stab) {
  int tid = threadIdx.x;
  int wid = tid >> 6, lane = tid & 63;

  float s3 = (lane & 16) ? -1.f : 1.f;
  float s7 = (lane & 8)  ? -1.f : 1.f;

#pragma unroll
  for (int u = 0; u < 5; ++u) {
    int idx = wid * 5 + u;              // 0..44, wave-uniform
    int pp = 0, base = 0, s = idx;
    while (s >= base + 9 - pp) { base += 9 - pp; ++pp; }
    int qq = pp + (s - base);

    const float4* rp = (const float4*)(G + pp * 256 + lane * 4);
    const float4* rq = (const float4*)(G + qq * 256 + lane * 4);
    float4 a0 = rp[0], a1 = rp[1];
    float4 b0 = rq[0], b1 = rq[1];

    // conj(a)*b summed over this lane's 4 k values
    float SR = a0.x*b0.x + a0.y*b0.y + a0.z*b0.z + a0.w*b0.w
             + a1.x*b1.x + a1.y*b1.y + a1.z*b1.z + a1.w*b1.w;
    float SI = a0.x*b0.y - a0.y*b0.x + a0.z*b0.w - a0.w*b0.z
             + a1.x*b1.y - a1.y*b1.x + a1.z*b1.w - a1.w*b1.z;

    float v0 = s3 * SR, v1 = s3 * SI, v2 = s7 * SR, v3 = s7 * SI;
#pragma unroll
    for (int m = 32; m >= 1; m >>= 1) {
      v0 += __shfl_xor(v0, m, 64);
      v1 += __shfl_xor(v1, m, 64);
      v2 += __shfl_xor(v2, m, 64);
      v3 += __shfl_xor(v3, m, 64);
    }
    if (lane == 0) {
      float sc = (pp == qq) ? 1.f : 2.f;  // Hermitian fold
      Stab[idx] = make_float4(sc * v0, sc * v1, sc * v2, sc * v3);
    }
  }
}

// ---- K3: per-element polynomial + MLP --------------------------------------
__global__ __launch_bounds__(256)
void qcnn_eval(const float* __restrict__ x, const float4* __restrict__ S,
               const float* __restrict__ W1, const float* __restrict__ b1,
               const float* __restrict__ W2, const float* __restrict__ b2,
               float* __restrict__ out, int B) {
  __shared__ float4 sh[45];
  int tid = threadIdx.x;
  if (tid < 45) sh[tid] = S[tid];
  __syncthreads();

  int i = blockIdx.x * 256 + tid;
  if (i >= B) return;

  float2 tp = reinterpret_cast<const float2*>(x)[i];
  float th = tp.x, ph = tp.y;

  float stt, ct;
  __sincosf(0.5f * th, &stt, &ct);

  float cpw[17], spw[17];
  cpw[0] = 1.f; spw[0] = 1.f;
#pragma unroll
  for (int k = 1; k < 17; ++k) { cpw[k] = cpw[k-1] * ct; spw[k] = spw[k-1] * stt; }

  float cd[9], sd[9];
  cd[0] = 1.f; sd[0] = 0.f;
  __sincosf(ph, &sd[1], &cd[1]);
#pragma unroll
  for (int d = 2; d < 9; ++d) {
    cd[d] = cd[d-1] * cd[1] - sd[d-1] * sd[1];
    sd[d] = sd[d-1] * cd[1] + cd[d-1] * sd[1];
  }

  float f3 = 0.f, f7 = 0.f;
  int sidx = 0;
#pragma unroll
  for (int pp = 0; pp < 9; ++pp) {
#pragma unroll
    for (int qq = pp; qq < 9; ++qq) {
      float4 s4 = sh[sidx]; ++sidx;
      float w = cpw[16 - pp - qq] * spw[pp + qq];
      int d = qq - pp;
      f3 += w * (s4.x * cd[d] - s4.y * sd[d]);
      f7 += w * (s4.z * cd[d] - s4.w * sd[d]);
    }
  }

  float acc = b2[0];
#pragma unroll
  for (int j = 0; j < 10; ++j) {
    float h = fast_tanh(f3 * W1[j] + f7 * W1[10 + j] + b1[j]);
    acc += h * W2[j];
  }
  out[i] = 1.f / (1.f + __expf(-acc));
}

extern "C" void kernel_launch(void* const* d_in, const int* in_sizes, int n_in,
                              void* d_out, int out_size, void* d_ws, size_t ws_size,
                              hipStream_t stream) {
  const float* x  = (const float*)d_in[0];
  const float* rz = (const float*)d_in[1];
  const float* ry = (const float*)d_in[2];
  const float* u3 = (const float*)d_in[3];
  const float* W1 = (const float*)d_in[4];
  const float* b1 = (const float*)d_in[5];
  const float* W2 = (const float*)d_in[6];
  const float* b2 = (const float*)d_in[7];

  float2* G    = (float2*)d_ws;                          // 9*256*8 = 18432 B
  float4* Stab = (float4*)((char*)d_ws + 20480);         // 45*16 = 720 B

  qcnn_sim<<<9, 64, 0, stream>>>(rz, ry, u3, G);
  qcnn_reduce<<<1, 576, 0, stream>>>(G, Stab);

  int B = in_sizes[0] / 2;                               // 65536
  qcnn_eval<<<(B + 255) / 256, 256, 0, stream>>>(x, (const float4*)Stab,
                                                 W1, b1, W2, b2,
                                                 (float*)d_out, B);
}